// Round 21
// baseline (328.699 us; speedup 1.0000x reference)
//
#include <hip/hip_runtime.h>

#define NB   4
#define NPTS 1024
#define HID  64
#define NU   1056    // (I,m) units per batch: sum_{m=0}^{31} (2m+2) = 32*33

typedef float f32x4 __attribute__((ext_vector_type(4)));
typedef float f32x2 __attribute__((ext_vector_type(2)));
typedef short bf16x8 __attribute__((ext_vector_type(8)));
typedef unsigned int u32;
typedef unsigned short u16;

// f32 -> bf16 RTNE (scalar, for precompute)
__device__ inline u16 f2bf(float x) {
    union { float f; unsigned u; } v; v.f = x;
    return (u16)((v.u + 0x7FFFu + ((v.u >> 16) & 1u)) >> 16);
}
// HW packed f32->bf16 (RTNE), one VALU op
__device__ inline u32 cvt_pk_bf16(float lo, float hi) {
    u32 r; asm("v_cvt_pk_bf16_f32 %0, %1, %2" : "=v"(r) : "v"(lo), "v"(hi)); return r;
}
// packed relu on 2x bf16 (bf16 order is monotone under signed-i16 compare)
__device__ inline u32 pk_relu2(u32 a) {
    u32 r; asm("v_pk_max_i16 %0, %1, 0" : "=v"(r) : "v"(a)); return r;
}

// Blocks 0..1023: P[b][n][k] = concat(pos,vel)[b][n][:] . W1[:][k]
// Block 1024:     W2T_bf16[ch][k] = bf16(W2[k][ch])   (8 KB, L2-resident)
__global__ __launch_bounds__(256) void precompute(
    const float* __restrict__ pos, const float* __restrict__ vel,
    const float* __restrict__ W1, const float* __restrict__ W2,
    float* __restrict__ P, u16* __restrict__ W2T) {
    if (blockIdx.x == NB * NPTS / 4) {
        for (int e = threadIdx.x; e < HID * HID; e += 256) {
            const int ch = e >> 6, k = e & 63;
            W2T[e] = f2bf(W2[k * HID + ch]);
        }
        return;
    }
    const int t   = blockIdx.x * 256 + threadIdx.x;
    const int row = t >> 6;          // b*NPTS + n
    const int k   = t & 63;
    const float* pp = pos + row * 3;
    const float* vv = vel + row * 3;
    float acc = 0.f;
    #pragma unroll
    for (int c = 0; c < 3; ++c) acc = fmaf(pp[c], W1[c * HID + k], acc);
    #pragma unroll
    for (int c = 0; c < 3; ++c) acc = fmaf(vv[c], W1[(3 + c) * HID + k], acc);
    P[row * HID + k] = acc;
}

// Apply W3 to a register-resident H tile (rows g*4+r, col-ch n*16+c),
// reduce over the 16 c-lanes, atomically add sgn-scaled 3-vectors into F.
__device__ inline void emit_tile(const f32x4 Ht[4], float sgn, int rowbase,
                                 const float* __restrict__ W3,
                                 float* __restrict__ F, int c, int g) {
    #pragma unroll
    for (int r = 0; r < 4; ++r) {
        float f0 = 0.f, f1 = 0.f, f2 = 0.f;
        #pragma unroll
        for (int n = 0; n < 4; ++n) {
            const int ch = n * 16 + c;
            const float h = Ht[n][r];
            f0 = fmaf(h, W3[ch * 3 + 0], f0);
            f1 = fmaf(h, W3[ch * 3 + 1], f1);
            f2 = fmaf(h, W3[ch * 3 + 2], f2);
        }
        #pragma unroll
        for (int off = 1; off < 16; off <<= 1) {
            f0 += __shfl_xor(f0, off, 64);
            f1 += __shfl_xor(f1, off, 64);
            f2 += __shfl_xor(f2, off, 64);
        }
        if (c < 3) {
            const float v = (c == 0) ? f0 : ((c == 1) ? f1 : f2);
            atomicAdd(&F[(size_t)(rowbase + g * 4 + r) * 3 + c], sgn * v);
        }
    }
}

// One j-subtile worth of work for one i-row. B fragments from LDS (per-lane
// 16B contiguous -> conflict-free ds_read_b128). Consume phase packed.
__device__ inline void do_jt(const f32x2* __restrict__ pj2,
                             const f32x2* __restrict__ bb2,
                             const f32x2* __restrict__ pi2,
                             const bf16x8* __restrict__ BfL,
                             const float* __restrict__ b2v,
                             bool accHj, f32x4* __restrict__ Hj,
                             float* __restrict__ qout) {
    union { bf16x8 v; u32 u[4]; } ap[2], am[2];
    #pragma unroll
    for (int kk = 0; kk < 2; ++kk)
        #pragma unroll
        for (int d = 0; d < 4; ++d) {
            f32x2 u  = pi2[kk * 4 + d] - pj2[kk * 4 + d];
            f32x2 tp = bb2[kk * 4 + d] - u;      // relu-arg, sign +
            f32x2 tm = bb2[kk * 4 + d] + u;      // relu-arg, sign -
            ap[kk].u[d] = pk_relu2(cvt_pk_bf16(tp.x, tp.y));
            am[kk].u[d] = pk_relu2(cvt_pk_bf16(tm.x, tm.y));
        }
    const f32x2 z2 = {0.f, 0.f};
    #pragma unroll
    for (int n = 0; n < 4; ++n) {
        const bf16x8 B0 = BfL[n * 64];
        const bf16x8 B1 = BfL[(4 + n) * 64];
        const f32x4 Ci = {b2v[n], b2v[n], b2v[n], b2v[n]};
        f32x4 Cp = __builtin_amdgcn_mfma_f32_16x16x32_bf16(ap[0].v, B0, Ci, 0, 0, 0);
        Cp       = __builtin_amdgcn_mfma_f32_16x16x32_bf16(ap[1].v, B1, Cp, 0, 0, 0);
        f32x4 Cm = __builtin_amdgcn_mfma_f32_16x16x32_bf16(am[0].v, B0, Ci, 0, 0, 0);
        Cm       = __builtin_amdgcn_mfma_f32_16x16x32_bf16(am[1].v, B1, Cm, 0, 0, 0);
        f32x2 cp01 = {Cp[0], Cp[1]}, cp23 = {Cp[2], Cp[3]};
        f32x2 cm01 = {Cm[0], Cm[1]}, cm23 = {Cm[2], Cm[3]};
        f32x2 d01 = __builtin_elementwise_max(cp01, z2) -
                    __builtin_elementwise_max(cm01, z2);
        f32x2 d23 = __builtin_elementwise_max(cp23, z2) -
                    __builtin_elementwise_max(cm23, z2);
        if (accHj) {
            f32x4 dd4 = {d01.x, d01.y, d23.x, d23.y};
            Hj[n] += dd4;
        }
        f32x2 q = d01 + d23;
        qout[n] = q.x + q.y;
    }
}

// Wave-unit = 16 i-rows x 32 j-rows macro-tile; ONE unit per 64-thread
// (1-wave) block. Rationale: 1-wave workgroups were the only packaging that
// exceeded 40% occupancy in this session (R5/R7: 42-43%); all 2/4-wave
// packagings of this kernel sit at 16-27% regardless of VGPR count.
// Body identical to R18 (best: 101.9 us).
__global__ __launch_bounds__(64, 4) void inet_pair(
    const float* __restrict__ P,  const float* __restrict__ b1,
    const u16* __restrict__ W2T,  const float* __restrict__ b2,
    const float* __restrict__ W3, float* __restrict__ F) {
    __shared__ __align__(16) u16 sBf[512 * 8];   // 8 frags x 64 lanes x 8 bf16 = 8 KB

    const int tid = threadIdx.x;
    // Stage B fragments: frag f=kk*4+n, lane l -> W2T[(n*16+cc)*64 + kk*32 + gg*8 ..+7]
    for (int s = tid; s < 512; s += 64) {
        const int f = s >> 6, l = s & 63;
        const int n = f & 3, kk = f >> 2, cc = l & 15, gg = l >> 4;
        ((uint4*)sBf)[s] = *(const uint4*)(W2T + (size_t)(n * 16 + cc) * HID + kk * 32 + gg * 8);
    }
    __syncthreads();

    const int lane = tid & 63;
    const int c    = lane & 15;
    const int g    = lane >> 4;
    const bf16x8* BfL = ((const bf16x8*)sBf) + lane;

    const int unit = blockIdx.x;                     // 0..NB*NU-1, one per wave
    const int b    = unit / NU;
    const int u    = unit - b * NU;
    // decode: units for macro m occupy [m(m+1), m(m+1)+2m+1]
    int m = (int)((sqrtf((float)(4 * u + 1)) - 1.0f) * 0.5f);
    while (m * (m + 1) > u) --m;
    while ((m + 1) * (m + 2) <= u) ++m;
    const int I  = u - m * (m + 1);                  // 0..2m+1
    const int J0 = 2 * m, J1 = 2 * m + 1;
    const bool jt0act = (I != J1);
    const bool diag0  = (I == J0);
    const bool diag1  = (I == J1);

    const float* Pb   = P + (size_t)b * NPTS * HID;
    const int    koff = g * 8;

    union V4 { f32x4 v; f32x2 p[2]; };

    // b1 k-slots (shared), pj for both j-subtiles
    f32x2 bb2[8], pj0[8], pj1[8];
    {
        V4 v0, v1, v2, v3;
        v0.v = *(const f32x4*)(b1 + koff);
        v1.v = *(const f32x4*)(b1 + koff + 4);
        v2.v = *(const f32x4*)(b1 + koff + 32);
        v3.v = *(const f32x4*)(b1 + koff + 36);
        bb2[0] = v0.p[0]; bb2[1] = v0.p[1]; bb2[2] = v1.p[0]; bb2[3] = v1.p[1];
        bb2[4] = v2.p[0]; bb2[5] = v2.p[1]; bb2[6] = v3.p[0]; bb2[7] = v3.p[1];
    }
    {
        const float* base = Pb + (size_t)(J0 * 16 + c) * HID + koff;
        V4 v0, v1, v2, v3;
        v0.v = *(const f32x4*)(base);
        v1.v = *(const f32x4*)(base + 4);
        v2.v = *(const f32x4*)(base + 32);
        v3.v = *(const f32x4*)(base + 36);
        pj0[0] = v0.p[0]; pj0[1] = v0.p[1]; pj0[2] = v1.p[0]; pj0[3] = v1.p[1];
        pj0[4] = v2.p[0]; pj0[5] = v2.p[1]; pj0[6] = v3.p[0]; pj0[7] = v3.p[1];
    }
    {
        const float* base = Pb + (size_t)(J1 * 16 + c) * HID + koff;
        V4 v0, v1, v2, v3;
        v0.v = *(const f32x4*)(base);
        v1.v = *(const f32x4*)(base + 4);
        v2.v = *(const f32x4*)(base + 32);
        v3.v = *(const f32x4*)(base + 36);
        pj1[0] = v0.p[0]; pj1[1] = v0.p[1]; pj1[2] = v1.p[0]; pj1[3] = v1.p[1];
        pj1[4] = v2.p[0]; pj1[5] = v2.p[1]; pj1[6] = v3.p[0]; pj1[7] = v3.p[1];
    }
    float b2v[4];
    #pragma unroll
    for (int n = 0; n < 4; ++n) b2v[n] = b2[n * 16 + c];

    f32x4 Hi[4], Hj0[4], Hj1[4];
    #pragma unroll
    for (int n = 0; n < 4; ++n) {
        Hi[n]  = (f32x4){0.f, 0.f, 0.f, 0.f};
        Hj0[n] = (f32x4){0.f, 0.f, 0.f, 0.f};
        Hj1[n] = (f32x4){0.f, 0.f, 0.f, 0.f};
    }

    const float* Pi0 = Pb + (size_t)(I * 16) * HID + koff;

    for (int i1 = 0; i1 < 4; ++i1) {            // dynamic: i-row group (proven schedule)
        const float selm = (g == i1) ? 1.0f : 0.0f;
        #pragma unroll
        for (int i2 = 0; i2 < 4; ++i2) {        // static: reg index within f32x4
            const float* pib = Pi0 + (size_t)(i1 * 4 + i2) * HID;
            V4 w0, w1, w2, w3;
            w0.v = *(const f32x4*)(pib);
            w1.v = *(const f32x4*)(pib + 4);
            w2.v = *(const f32x4*)(pib + 32);
            w3.v = *(const f32x4*)(pib + 36);
            f32x2 pi2[8];
            pi2[0] = w0.p[0]; pi2[1] = w0.p[1]; pi2[2] = w1.p[0]; pi2[3] = w1.p[1];
            pi2[4] = w2.p[0]; pi2[5] = w2.p[1]; pi2[6] = w3.p[0]; pi2[7] = w3.p[1];

            float q0[4], q1[4];
            if (jt0act) {
                do_jt(pj0, bb2, pi2, BfL, b2v, !diag0, Hj0, q0);
            } else {
                q0[0] = q0[1] = q0[2] = q0[3] = 0.f;
            }
            do_jt(pj1, bb2, pi2, BfL, b2v, !diag1, Hj1, q1);

            // combined row-sum over 32 j's -> ONE shuffle-reduce per (i,n)
            #pragma unroll
            for (int n = 0; n < 4; ++n) {
                float s = q0[n] + q1[n];
                s += __shfl_xor(s, 16, 64);
                s += __shfl_xor(s, 32, 64);
                Hi[n][i2] = fmaf(selm, s, Hi[n][i2]);
            }
        }
    }

    const int rowbase = b * NPTS;
    emit_tile(Hi, 0.5f, rowbase + I * 16, W3, F, c, g);             // H[i] += d
    if (jt0act && !diag0)
        emit_tile(Hj0, -0.5f, rowbase + J0 * 16, W3, F, c, g);      // H[j0] -= d
    if (!diag1)
        emit_tile(Hj1, -0.5f, rowbase + J1 * 16, W3, F, c, g);      // H[j1] -= d
}

extern "C" void kernel_launch(void* const* d_in, const int* in_sizes, int n_in,
                              void* d_out, int out_size, void* d_ws, size_t ws_size,
                              hipStream_t stream) {
    const float* pos = (const float*)d_in[0];
    const float* vel = (const float*)d_in[1];
    const float* W1  = (const float*)d_in[2];
    const float* b1  = (const float*)d_in[3];
    const float* W2  = (const float*)d_in[4];
    const float* b2  = (const float*)d_in[5];
    const float* W3  = (const float*)d_in[6];
    const float* b3  = (const float*)d_in[7];   // cancels in antisymmetrization
    (void)b3;
    float* out = (float*)d_out;
    float* P   = (float*)d_ws;                                        // 1 MB
    u16*   W2T = (u16*)((char*)d_ws + (size_t)NB * NPTS * HID * 4);   // 8 KB

    hipMemsetAsync(out, 0, (size_t)out_size * sizeof(float), stream);
    precompute<<<dim3(NB * NPTS / 4 + 1), dim3(256), 0, stream>>>(pos, vel, W1, W2, P, W2T);
    // 4 batches x 1056 macro units; ONE unit per 64-thread (1-wave) block
    inet_pair<<<dim3(NB * NU), dim3(64), 0, stream>>>(P, b1, W2T, b2, W3, out);
}

// Round 22
// 101.711 us; speedup vs baseline: 3.2317x; 3.2317x over previous
//
#include <hip/hip_runtime.h>

#define NB   4
#define NPTS 1024
#define HID  64
#define NU   1056    // (I,m) units per batch: sum_{m=0}^{31} (2m+2) = 32*33

typedef float f32x4 __attribute__((ext_vector_type(4)));
typedef float f32x2 __attribute__((ext_vector_type(2)));
typedef short bf16x8 __attribute__((ext_vector_type(8)));
typedef unsigned int u32;
typedef unsigned short u16;

// f32 -> bf16 RTNE (scalar, for precompute)
__device__ inline u16 f2bf(float x) {
    union { float f; unsigned u; } v; v.f = x;
    return (u16)((v.u + 0x7FFFu + ((v.u >> 16) & 1u)) >> 16);
}
// HW packed f32->bf16 (RTNE), one VALU op
__device__ inline u32 cvt_pk_bf16(float lo, float hi) {
    u32 r; asm("v_cvt_pk_bf16_f32 %0, %1, %2" : "=v"(r) : "v"(lo), "v"(hi)); return r;
}
// packed relu on 2x bf16 (bf16 order is monotone under signed-i16 compare)
__device__ inline u32 pk_relu2(u32 a) {
    u32 r; asm("v_pk_max_i16 %0, %1, 0" : "=v"(r) : "v"(a)); return r;
}

// Blocks 0..1023: P[b][n][k] = concat(pos,vel)[b][n][:] . W1[:][k]
// Block 1024:     W2T_bf16[ch][k] = bf16(W2[k][ch])   (8 KB, L2-resident)
__global__ __launch_bounds__(256) void precompute(
    const float* __restrict__ pos, const float* __restrict__ vel,
    const float* __restrict__ W1, const float* __restrict__ W2,
    float* __restrict__ P, u16* __restrict__ W2T) {
    if (blockIdx.x == NB * NPTS / 4) {
        for (int e = threadIdx.x; e < HID * HID; e += 256) {
            const int ch = e >> 6, k = e & 63;
            W2T[e] = f2bf(W2[k * HID + ch]);
        }
        return;
    }
    const int t   = blockIdx.x * 256 + threadIdx.x;
    const int row = t >> 6;          // b*NPTS + n
    const int k   = t & 63;
    const float* pp = pos + row * 3;
    const float* vv = vel + row * 3;
    float acc = 0.f;
    #pragma unroll
    for (int c = 0; c < 3; ++c) acc = fmaf(pp[c], W1[c * HID + k], acc);
    #pragma unroll
    for (int c = 0; c < 3; ++c) acc = fmaf(vv[c], W1[(3 + c) * HID + k], acc);
    P[row * HID + k] = acc;
}

// Apply W3 to a register-resident H tile (rows g*4+r, col-ch n*16+c),
// reduce over the 16 c-lanes, atomically add sgn-scaled 3-vectors into F.
__device__ inline void emit_tile(const f32x4 Ht[4], float sgn, int rowbase,
                                 const float* __restrict__ W3,
                                 float* __restrict__ F, int c, int g) {
    #pragma unroll
    for (int r = 0; r < 4; ++r) {
        float f0 = 0.f, f1 = 0.f, f2 = 0.f;
        #pragma unroll
        for (int n = 0; n < 4; ++n) {
            const int ch = n * 16 + c;
            const float h = Ht[n][r];
            f0 = fmaf(h, W3[ch * 3 + 0], f0);
            f1 = fmaf(h, W3[ch * 3 + 1], f1);
            f2 = fmaf(h, W3[ch * 3 + 2], f2);
        }
        #pragma unroll
        for (int off = 1; off < 16; off <<= 1) {
            f0 += __shfl_xor(f0, off, 64);
            f1 += __shfl_xor(f1, off, 64);
            f2 += __shfl_xor(f2, off, 64);
        }
        if (c < 3) {
            const float v = (c == 0) ? f0 : ((c == 1) ? f1 : f2);
            atomicAdd(&F[(size_t)(rowbase + g * 4 + r) * 3 + c], sgn * v);
        }
    }
}

// One j-subtile worth of work for one i-row. B fragments from LDS (per-lane
// 16B contiguous -> conflict-free ds_read_b128). Consume phase packed.
__device__ inline void do_jt(const f32x2* __restrict__ pj2,
                             const f32x2* __restrict__ bb2,
                             const f32x2* __restrict__ pi2,
                             const bf16x8* __restrict__ BfL,
                             const float* __restrict__ b2v,
                             bool accHj, f32x4* __restrict__ Hj,
                             float* __restrict__ qout) {
    union { bf16x8 v; u32 u[4]; } ap[2], am[2];
    #pragma unroll
    for (int kk = 0; kk < 2; ++kk)
        #pragma unroll
        for (int d = 0; d < 4; ++d) {
            f32x2 u  = pi2[kk * 4 + d] - pj2[kk * 4 + d];
            f32x2 tp = bb2[kk * 4 + d] - u;      // relu-arg, sign +
            f32x2 tm = bb2[kk * 4 + d] + u;      // relu-arg, sign -
            ap[kk].u[d] = pk_relu2(cvt_pk_bf16(tp.x, tp.y));
            am[kk].u[d] = pk_relu2(cvt_pk_bf16(tm.x, tm.y));
        }
    const f32x2 z2 = {0.f, 0.f};
    #pragma unroll
    for (int n = 0; n < 4; ++n) {
        const bf16x8 B0 = BfL[n * 64];
        const bf16x8 B1 = BfL[(4 + n) * 64];
        const f32x4 Ci = {b2v[n], b2v[n], b2v[n], b2v[n]};
        f32x4 Cp = __builtin_amdgcn_mfma_f32_16x16x32_bf16(ap[0].v, B0, Ci, 0, 0, 0);
        Cp       = __builtin_amdgcn_mfma_f32_16x16x32_bf16(ap[1].v, B1, Cp, 0, 0, 0);
        f32x4 Cm = __builtin_amdgcn_mfma_f32_16x16x32_bf16(am[0].v, B0, Ci, 0, 0, 0);
        Cm       = __builtin_amdgcn_mfma_f32_16x16x32_bf16(am[1].v, B1, Cm, 0, 0, 0);
        f32x2 cp01 = {Cp[0], Cp[1]}, cp23 = {Cp[2], Cp[3]};
        f32x2 cm01 = {Cm[0], Cm[1]}, cm23 = {Cm[2], Cm[3]};
        f32x2 d01 = __builtin_elementwise_max(cp01, z2) -
                    __builtin_elementwise_max(cm01, z2);
        f32x2 d23 = __builtin_elementwise_max(cp23, z2) -
                    __builtin_elementwise_max(cm23, z2);
        if (accHj) {
            f32x4 dd4 = {d01.x, d01.y, d23.x, d23.y};
            Hj[n] += dd4;
        }
        f32x2 q = d01 + d23;
        qout[n] = q.x + q.y;
    }
}

// Wave-unit = 16 i-rows x 32 j-rows macro-tile; ONE unit per 64-thread
// (1-wave) block. R20 showed 1-wave packing raises occupancy (23-37%) but
// launch_bounds(64,4)'s 128-reg budget squeezed VGPR to 64 -> 593MB spill.
// (64,2) = 256-reg budget: the envelope this body provably fits (R11/R18).
__global__ __launch_bounds__(64, 2) void inet_pair(
    const float* __restrict__ P,  const float* __restrict__ b1,
    const u16* __restrict__ W2T,  const float* __restrict__ b2,
    const float* __restrict__ W3, float* __restrict__ F) {
    __shared__ __align__(16) u16 sBf[512 * 8];   // 8 frags x 64 lanes x 8 bf16 = 8 KB

    const int tid = threadIdx.x;
    // Stage B fragments: frag f=kk*4+n, lane l -> W2T[(n*16+cc)*64 + kk*32 + gg*8 ..+7]
    for (int s = tid; s < 512; s += 64) {
        const int f = s >> 6, l = s & 63;
        const int n = f & 3, kk = f >> 2, cc = l & 15, gg = l >> 4;
        ((uint4*)sBf)[s] = *(const uint4*)(W2T + (size_t)(n * 16 + cc) * HID + kk * 32 + gg * 8);
    }
    __syncthreads();

    const int lane = tid & 63;
    const int c    = lane & 15;
    const int g    = lane >> 4;
    const bf16x8* BfL = ((const bf16x8*)sBf) + lane;

    const int unit = blockIdx.x;                     // 0..NB*NU-1, one per wave
    const int b    = unit / NU;
    const int u    = unit - b * NU;
    // decode: units for macro m occupy [m(m+1), m(m+1)+2m+1]
    int m = (int)((sqrtf((float)(4 * u + 1)) - 1.0f) * 0.5f);
    while (m * (m + 1) > u) --m;
    while ((m + 1) * (m + 2) <= u) ++m;
    const int I  = u - m * (m + 1);                  // 0..2m+1
    const int J0 = 2 * m, J1 = 2 * m + 1;
    const bool jt0act = (I != J1);
    const bool diag0  = (I == J0);
    const bool diag1  = (I == J1);

    const float* Pb   = P + (size_t)b * NPTS * HID;
    const int    koff = g * 8;

    union V4 { f32x4 v; f32x2 p[2]; };

    // b1 k-slots (shared), pj for both j-subtiles
    f32x2 bb2[8], pj0[8], pj1[8];
    {
        V4 v0, v1, v2, v3;
        v0.v = *(const f32x4*)(b1 + koff);
        v1.v = *(const f32x4*)(b1 + koff + 4);
        v2.v = *(const f32x4*)(b1 + koff + 32);
        v3.v = *(const f32x4*)(b1 + koff + 36);
        bb2[0] = v0.p[0]; bb2[1] = v0.p[1]; bb2[2] = v1.p[0]; bb2[3] = v1.p[1];
        bb2[4] = v2.p[0]; bb2[5] = v2.p[1]; bb2[6] = v3.p[0]; bb2[7] = v3.p[1];
    }
    {
        const float* base = Pb + (size_t)(J0 * 16 + c) * HID + koff;
        V4 v0, v1, v2, v3;
        v0.v = *(const f32x4*)(base);
        v1.v = *(const f32x4*)(base + 4);
        v2.v = *(const f32x4*)(base + 32);
        v3.v = *(const f32x4*)(base + 36);
        pj0[0] = v0.p[0]; pj0[1] = v0.p[1]; pj0[2] = v1.p[0]; pj0[3] = v1.p[1];
        pj0[4] = v2.p[0]; pj0[5] = v2.p[1]; pj0[6] = v3.p[0]; pj0[7] = v3.p[1];
    }
    {
        const float* base = Pb + (size_t)(J1 * 16 + c) * HID + koff;
        V4 v0, v1, v2, v3;
        v0.v = *(const f32x4*)(base);
        v1.v = *(const f32x4*)(base + 4);
        v2.v = *(const f32x4*)(base + 32);
        v3.v = *(const f32x4*)(base + 36);
        pj1[0] = v0.p[0]; pj1[1] = v0.p[1]; pj1[2] = v1.p[0]; pj1[3] = v1.p[1];
        pj1[4] = v2.p[0]; pj1[5] = v2.p[1]; pj1[6] = v3.p[0]; pj1[7] = v3.p[1];
    }
    float b2v[4];
    #pragma unroll
    for (int n = 0; n < 4; ++n) b2v[n] = b2[n * 16 + c];

    f32x4 Hi[4], Hj0[4], Hj1[4];
    #pragma unroll
    for (int n = 0; n < 4; ++n) {
        Hi[n]  = (f32x4){0.f, 0.f, 0.f, 0.f};
        Hj0[n] = (f32x4){0.f, 0.f, 0.f, 0.f};
        Hj1[n] = (f32x4){0.f, 0.f, 0.f, 0.f};
    }

    const float* Pi0 = Pb + (size_t)(I * 16) * HID + koff;

    for (int i1 = 0; i1 < 4; ++i1) {            // dynamic: i-row group (proven schedule)
        const float selm = (g == i1) ? 1.0f : 0.0f;
        #pragma unroll
        for (int i2 = 0; i2 < 4; ++i2) {        // static: reg index within f32x4
            const float* pib = Pi0 + (size_t)(i1 * 4 + i2) * HID;
            V4 w0, w1, w2, w3;
            w0.v = *(const f32x4*)(pib);
            w1.v = *(const f32x4*)(pib + 4);
            w2.v = *(const f32x4*)(pib + 32);
            w3.v = *(const f32x4*)(pib + 36);
            f32x2 pi2[8];
            pi2[0] = w0.p[0]; pi2[1] = w0.p[1]; pi2[2] = w1.p[0]; pi2[3] = w1.p[1];
            pi2[4] = w2.p[0]; pi2[5] = w2.p[1]; pi2[6] = w3.p[0]; pi2[7] = w3.p[1];

            float q0[4], q1[4];
            if (jt0act) {
                do_jt(pj0, bb2, pi2, BfL, b2v, !diag0, Hj0, q0);
            } else {
                q0[0] = q0[1] = q0[2] = q0[3] = 0.f;
            }
            do_jt(pj1, bb2, pi2, BfL, b2v, !diag1, Hj1, q1);

            // combined row-sum over 32 j's -> ONE shuffle-reduce per (i,n)
            #pragma unroll
            for (int n = 0; n < 4; ++n) {
                float s = q0[n] + q1[n];
                s += __shfl_xor(s, 16, 64);
                s += __shfl_xor(s, 32, 64);
                Hi[n][i2] = fmaf(selm, s, Hi[n][i2]);
            }
        }
    }

    const int rowbase = b * NPTS;
    emit_tile(Hi, 0.5f, rowbase + I * 16, W3, F, c, g);             // H[i] += d
    if (jt0act && !diag0)
        emit_tile(Hj0, -0.5f, rowbase + J0 * 16, W3, F, c, g);      // H[j0] -= d
    if (!diag1)
        emit_tile(Hj1, -0.5f, rowbase + J1 * 16, W3, F, c, g);      // H[j1] -= d
}

extern "C" void kernel_launch(void* const* d_in, const int* in_sizes, int n_in,
                              void* d_out, int out_size, void* d_ws, size_t ws_size,
                              hipStream_t stream) {
    const float* pos = (const float*)d_in[0];
    const float* vel = (const float*)d_in[1];
    const float* W1  = (const float*)d_in[2];
    const float* b1  = (const float*)d_in[3];
    const float* W2  = (const float*)d_in[4];
    const float* b2  = (const float*)d_in[5];
    const float* W3  = (const float*)d_in[6];
    const float* b3  = (const float*)d_in[7];   // cancels in antisymmetrization
    (void)b3;
    float* out = (float*)d_out;
    float* P   = (float*)d_ws;                                        // 1 MB
    u16*   W2T = (u16*)((char*)d_ws + (size_t)NB * NPTS * HID * 4);   // 8 KB

    hipMemsetAsync(out, 0, (size_t)out_size * sizeof(float), stream);
    precompute<<<dim3(NB * NPTS / 4 + 1), dim3(256), 0, stream>>>(pos, vel, W1, W2, P, W2T);
    // 4 batches x 1056 macro units; ONE unit per 64-thread (1-wave) block
    inet_pair<<<dim3(NB * NU), dim3(64), 0, stream>>>(P, b1, W2T, b2, W3, out);
}